// Round 18
// baseline (149.666 us; speedup 1.0000x reference)
//
#include <hip/hip_runtime.h>
#include <hip/hip_bf16.h>

// HET relational attention layer. (R18 = R17 + agg pass-B dedup: each half-wave
//   accumulates ONLY its own edge stream (even/odd), single shfl_xor(32) merge at end
//   — halves pass-B FMAs and deletes per-iteration shuffles. Scatter CHUNK 4096->2048.)
//  memset         : gCursor = 0.
//  K1 wext_scatter: blocks <288 fragment-major W_ext; blocks >=288 bucket_scatter into
//                   FIXED regions (b*CAP), LDS hist + 1 atomic/bucket/block. CHUNK=2048.
//  K2 gemm_place  : blocks <782: gemm (4 waves, 32 rows/wave, 128 rows/block, 576 cols;
//                   A f32->bf16 via XOR-swizzled LDS; B per-cb 16KB LDS w/ reg-prefetch;
//                   C via swizzled LDS -> coalesced PLAIN 1KB stores; projR [rel][node][64],
//                   elrb [node][64] bf16). blocks >=782: exact_place (one per bucket).
//  K3 agg         : 1 wave per dst node; fast path deg<=64: exp once/edge -> LDS,
//                   half-wave-owned paired gather + end merge.

#define NN 100000
#define NNP 100096            // 782*128
#define NE 1600000
#define NH 4
#define INF_ 128
#define DH 16
#define NCOL 576
#define LEAKY 0.2f
#define NBUCK 391
#define BSHIFT 8
#define CHUNK 2048
#define NSCAT 782             // ceil(NE/CHUNK)
#define CAP 5120
#define GEMM_BLOCKS 782
#define WEXT_BLOCKS 288

typedef __hip_bfloat16 bf16;
typedef __attribute__((ext_vector_type(8))) short bf16x8;
typedef __attribute__((ext_vector_type(4))) short bf16x4;
typedef __attribute__((ext_vector_type(4))) float f32x4;

static __device__ __forceinline__ short f2bs(float x) {
    bf16 b = __float2bfloat16(x);
    return *reinterpret_cast<short*>(&b);
}
static __device__ __forceinline__ float bflo(unsigned u) { return __uint_as_float(u << 16); }
static __device__ __forceinline__ float bfhi(unsigned u) { return __uint_as_float(u & 0xffff0000u); }
static __device__ __forceinline__ float b2f(short us) {
    return __uint_as_float(((unsigned)(unsigned short)us) << 16);
}

// blocks <288: fragment-major W_ext. blocks >=288: bucket_scatter (gCursor pre-zeroed).
__global__ __launch_bounds__(256) void wext_scatter(
    const float* __restrict__ W, const float* __restrict__ al, const float* __restrict__ ar,
    short* __restrict__ wxt2,
    const int* __restrict__ src, const int* __restrict__ dst, const int* __restrict__ rel,
    int* __restrict__ gCursor, int* __restrict__ pairbuf) {
    __shared__ int hist[NBUCK];
    int t = threadIdx.x;

    if (blockIdx.x >= WEXT_BLOCKS) {
        int blk = blockIdx.x - WEXT_BLOCKS;
        for (int i = t; i < NBUCK; i += 256) hist[i] = 0;
        __syncthreads();
        int base = blk * CHUNK;
        #pragma unroll
        for (int j = 0; j < CHUNK / 256; ++j) {
            int e = base + j * 256 + t;
            if (e < NE) atomicAdd(&hist[dst[e] >> BSHIFT], 1);
        }
        __syncthreads();
        for (int i = t; i < NBUCK; i += 256) {
            int v = hist[i];
            hist[i] = v ? (i * CAP + atomicAdd(&gCursor[i], v)) : 0;
        }
        __syncthreads();
        #pragma unroll
        for (int j = 0; j < CHUNK / 256; ++j) {
            int e = base + j * 256 + t;
            if (e < NE) {
                int d = dst[e];
                int b = d >> BSHIFT;
                int rec = ((d & 255) << 20) | (src[e] * 8 + rel[e]);
                int pos = atomicAdd(&hist[b], 1);
                pairbuf[pos] = rec;
            }
        }
        return;
    }

    int idx = blockIdx.x * 256 + t;
    int e = idx & 7, lane = (idx >> 3) & 63, ct = (idx >> 9) & 3, ks = (idx >> 11) & 3, cb = idx >> 13;
    int g = lane >> 4, r = lane & 15;
    int c = cb * 64 + ct * 16 + r;
    int k = ks * 32 + g * 8 + e;
    float v;
    if (c < 512) {
        int rr = c >> 6, rem = c & 63, h = rem >> 4, d = rem & 15;
        v = W[((rr * NH + h) * INF_ + k) * DH + d];
    } else {
        int rh = c - 512;
        const float* a = al;
        if (rh >= 32) { rh -= 32; a = ar; }
        int rr = rh >> 2, h = rh & 3;
        const float* wp = &W[((rr * NH + h) * INF_ + k) * DH];
        const float* ap = &a[(rr * NH + h) * DH];
        float s = 0.f;
        #pragma unroll
        for (int d = 0; d < DH; ++d) s += wp[d] * ap[d];
        v = s;
    }
    wxt2[idx] = f2bs(v);
}

// Fused: gemm (blocks < GEMM_BLOCKS) + exact_place (blocks >= GEMM_BLOCKS).
__global__ __launch_bounds__(256) void gemm_place(
    const float* __restrict__ A, const short* __restrict__ WxT2,
    short* __restrict__ projR, short* __restrict__ elrb,
    const int* __restrict__ gCursor, const int* __restrict__ pairbuf,
    int2* __restrict__ offdeg, int* __restrict__ rec) {
    __shared__ short As[16384];          // 32 KB: A-tile / C-slices (gemm) or hist/tsum (place)
    __shared__ short Bs[8192];           // 16 KB: current cb's B tile (gemm only)
    int t = threadIdx.x;

    if (blockIdx.x >= GEMM_BLOCKS) {
        // ---- exact_place: one block per bucket (pairbuf complete after K1) ----
        int* hist = (int*)As;
        int* tsum = hist + 256;
        int b = blockIdx.x - GEMM_BLOCKS;
        int start = b * CAP, cnt = gCursor[b];
        hist[t] = 0;
        __syncthreads();
        for (int i = t; i < cnt; i += 256) atomicAdd(&hist[pairbuf[start + i] >> 20], 1);
        __syncthreads();
        int own = hist[t];
        tsum[t] = own;
        __syncthreads();
        for (int st = 1; st < 256; st <<= 1) {
            int y = (t >= st) ? tsum[t - st] : 0;
            __syncthreads();
            tsum[t] += y;
            __syncthreads();
        }
        int excl = start + tsum[t] - own;
        int node = b * 256 + t;
        if (node < NN) offdeg[node] = make_int2(excl, own);
        __syncthreads();
        hist[t] = excl;
        __syncthreads();
        for (int i = t; i < cnt; i += 256) {
            int rc = pairbuf[start + i];
            int pos = atomicAdd(&hist[rc >> 20], 1);
            int sr = rc & 0xFFFFF;
            rec[pos] = (sr >> 3) * 64 + (sr & 7) * 4;   // elrb index; s=rv>>6, r=(rv&63)>>2
        }
        return;
    }

    // ---- gemm: 4 waves, 32 rows/wave, 128 rows/block, all 576 cols; B via LDS pipeline ----
    int wv = t >> 6, lane = t & 63;
    int n0 = blockIdx.x * 128;
    int g = lane >> 4, r = lane & 15;

    #pragma unroll
    for (int j = 0; j < 8; ++j) {
        int i = j * 256 + t;
        int row = i >> 4, c8 = i & 15;
        int gr = n0 + row;
        bf16x8 v;
        if (gr < NN) {
            float4 f0 = *(const float4*)&A[gr * INF_ + c8 * 8];
            float4 f1 = *(const float4*)&A[gr * INF_ + c8 * 8 + 4];
            v[0] = f2bs(f0.x); v[1] = f2bs(f0.y); v[2] = f2bs(f0.z); v[3] = f2bs(f0.w);
            v[4] = f2bs(f1.x); v[5] = f2bs(f1.y); v[6] = f2bs(f1.z); v[7] = f2bs(f1.w);
        } else {
            v = (bf16x8)(short)0;
        }
        *(bf16x8*)&As[(row * 16 + (c8 ^ (row & 7))) * 8] = v;
    }
    // Prefetch cb=0's B into regs (overlaps the staging barrier).
    bf16x8 breg[4];
    #pragma unroll
    for (int q = 0; q < 4; ++q)
        breg[q] = *(const bf16x8*)&WxT2[(q * 256 + t) * 8];
    __syncthreads();

    bf16x8 afr[2][4];
    #pragma unroll
    for (int nt = 0; nt < 2; ++nt) {
        int row = wv * 32 + nt * 16 + r;
        #pragma unroll
        for (int ks = 0; ks < 4; ++ks)
            afr[nt][ks] = *(const bf16x8*)&As[(row * 16 + ((ks * 4 + g) ^ (r & 7))) * 8];
    }
    __syncthreads();                      // A-tile dead; reuse as C-stage
    short* Csh = &As[wv * 4096];          // per-wave 8 KB slice
    int n0w = n0 + wv * 32;

    for (int cb = 0; cb < 9; ++cb) {
        // write-late: B regs -> LDS (Bs free: end-of-prev-cb syncthreads).
        #pragma unroll
        for (int q = 0; q < 4; ++q)
            *(bf16x8*)&Bs[(q * 256 + t) * 8] = breg[q];
        __syncthreads();
        // issue-early: prefetch next cb's B during MFMA + C-stage below.
        if (cb < 8) {
            #pragma unroll
            for (int q = 0; q < 4; ++q)
                breg[q] = *(const bf16x8*)&WxT2[((cb + 1) * 1024 + q * 256 + t) * 8];
        }

        f32x4 acc[2][4] = {};
        #pragma unroll
        for (int ks = 0; ks < 4; ++ks) {
            #pragma unroll
            for (int ct = 0; ct < 4; ++ct) {
                bf16x8 b = *(const bf16x8*)&Bs[((ks * 4 + ct) * 64 + lane) * 8];
                acc[0][ct] = __builtin_amdgcn_mfma_f32_16x16x32_bf16(b, afr[0][ks], acc[0][ct], 0, 0, 0);
                acc[1][ct] = __builtin_amdgcn_mfma_f32_16x16x32_bf16(b, afr[1][ks], acc[1][ct], 0, 0, 0);
            }
        }
        // lane(g,r), reg q: row = n0w + nt*16 + r, col = cb*64 + ct*16 + g*4 + q.
        // Unified bf16 C-stage: cb<8 -> projR[cb][node][64]; cb==8 -> elrb[node][64].
        #pragma unroll
        for (int nt = 0; nt < 2; ++nt) {
            int rr = nt * 16 + r;
            #pragma unroll
            for (int ct = 0; ct < 4; ++ct) {
                bf16x4 p;
                p[0] = f2bs(acc[nt][ct][0]); p[1] = f2bs(acc[nt][ct][1]);
                p[2] = f2bs(acc[nt][ct][2]); p[3] = f2bs(acc[nt][ct][3]);
                *(bf16x4*)&Csh[rr * 64 + (((ct * 4 + g) ^ ((rr & 7) << 1)) << 2)] = p;
            }
        }
        __builtin_amdgcn_wave_barrier();
        short* dstbase = (cb < 8) ? &projR[((size_t)cb * NN + n0w) * 64]
                                  : &elrb[(size_t)n0w * 64];
        #pragma unroll
        for (int q = 0; q < 4; ++q) {
            int rr = (lane >> 3) + q * 8;
            if (n0w + rr < NN) {
                bf16x8 vv = *(const bf16x8*)&Csh[rr * 64 + (((lane & 7) ^ (rr & 7)) << 3)];
                *(bf16x8*)&dstbase[q * 512 + lane * 8] = vv;
            }
        }
        __syncthreads();                  // C-stage read done AND B reads done before next cb
    }
}

__global__ __launch_bounds__(256) void agg(
    const int2* __restrict__ offdeg, const int* __restrict__ rec,
    const short* __restrict__ elrb, const bf16* __restrict__ projR,
    const float* __restrict__ bias, float* __restrict__ out) {
    __shared__ float s_alpha[4][64][4];
    __shared__ int   s_pidx[4][64];
    __shared__ float s_er[4][32];
    int wv = threadIdx.x >> 6, lane = threadIdx.x & 63;
    int d = blockIdx.x * 4 + wv;
    if (d >= NN) return;
    int2 od = offdeg[d];
    int off = od.x, deg = od.y;
    int end = off + deg;

    if (lane < 32) s_er[wv][lane] = b2f(elrb[d * 64 + 32 + lane]);
    __builtin_amdgcn_wave_barrier();
    asm volatile("s_waitcnt lgkmcnt(0)" ::: "memory");

    if (deg == 0) {
        if (lane < 32) {
            float2 bb = *(const float2*)&bias[lane * 2];
            *(float2*)&out[d * 64 + lane * 2] = bb;
        }
    } else if (deg <= 64) {
        int i = off + lane;
        float e0 = 0.f, e1 = 0.f, e2 = 0.f, e3 = 0.f;
        int pidx = 0;
        if (i < end) {
            int rv = rec[i];
            pidx = ((rv & 63) >> 2) * (NN * 64) + (rv >> 6) * 64;
            bf16x4 el4 = *(const bf16x4*)&elrb[rv];
            int erb = rv & 63;            // r*4
            float x;
            x = b2f(el4[0]) + s_er[wv][erb + 0]; x = x > 0.f ? x : LEAKY * x; e0 = __expf(x);
            x = b2f(el4[1]) + s_er[wv][erb + 1]; x = x > 0.f ? x : LEAKY * x; e1 = __expf(x);
            x = b2f(el4[2]) + s_er[wv][erb + 2]; x = x > 0.f ? x : LEAKY * x; e2 = __expf(x);
            x = b2f(el4[3]) + s_er[wv][erb + 3]; x = x > 0.f ? x : LEAKY * x; e3 = __expf(x);
        }
        s_pidx[wv][lane] = pidx;
        *(float4*)&s_alpha[wv][lane][0] = make_float4(e0, e1, e2, e3);
        __builtin_amdgcn_wave_barrier();
        asm volatile("s_waitcnt lgkmcnt(0)" ::: "memory");

        // pass B: half-wave hl owns edge stream (j+hl for each pair); columns 2c,2c+1.
        // Cross-half merge ONCE at the end (replaces per-iteration shfl + dual FMAs).
        int col2 = (lane & 31) * 2;
        int hl = lane >> 5;
        int h2 = (lane & 31) >> 3;
        float acc0 = 0.f, acc1 = 0.f, dsum = 0.f;
        int j = 0;
        for (; j + 8 <= deg; j += 8) {        // 4 loads in flight, own-edge only
            unsigned uu[4];
            float aa[4];
            #pragma unroll
            for (int p = 0; p < 4; ++p) {
                int eidx = j + 2 * p + hl;
                uu[p] = *(const unsigned*)&projR[s_pidx[wv][eidx] + col2];
                aa[p] = s_alpha[wv][eidx][h2];
            }
            #pragma unroll
            for (int p = 0; p < 4; ++p) {
                acc0 = fmaf(aa[p], bflo(uu[p]), acc0);
                acc1 = fmaf(aa[p], bfhi(uu[p]), acc1);
                dsum += aa[p];
            }
        }
        for (; j + 2 <= deg; j += 2) {
            int eidx = j + hl;
            unsigned u = *(const unsigned*)&projR[s_pidx[wv][eidx] + col2];
            float a = s_alpha[wv][eidx][h2];
            acc0 = fmaf(a, bflo(u), acc0);
            acc1 = fmaf(a, bfhi(u), acc1);
            dsum += a;
        }
        if (j < deg && hl == 0) {             // odd tail: low half only
            unsigned u = *(const unsigned*)&projR[s_pidx[wv][j] + col2];
            float a = s_alpha[wv][j][h2];
            acc0 = fmaf(a, bflo(u), acc0);
            acc1 = fmaf(a, bfhi(u), acc1);
            dsum += a;
        }
        acc0 += __shfl_xor(acc0, 32);
        acc1 += __shfl_xor(acc1, 32);
        dsum += __shfl_xor(dsum, 32);
        if (lane < 32) {
            float inv = 1.0f / dsum;
            float2 bb = *(const float2*)&bias[col2];
            float2 o;
            o.x = acc0 * inv + bb.x;
            o.y = acc1 * inv + bb.y;
            *(float2*)&out[d * 64 + col2] = o;
        }
    } else {
        int c = lane, h = c >> 4;
        float dsum0 = 0.f, dsum1 = 0.f, dsum2 = 0.f, dsum3 = 0.f;
        for (int i = off + lane; i < end; i += 64) {
            int rv = rec[i];
            bf16x4 el4 = *(const bf16x4*)&elrb[rv];
            int erb = rv & 63;
            float x;
            x = b2f(el4[0]) + s_er[wv][erb + 0]; x = x > 0.f ? x : LEAKY * x; dsum0 += __expf(x);
            x = b2f(el4[1]) + s_er[wv][erb + 1]; x = x > 0.f ? x : LEAKY * x; dsum1 += __expf(x);
            x = b2f(el4[2]) + s_er[wv][erb + 2]; x = x > 0.f ? x : LEAKY * x; dsum2 += __expf(x);
            x = b2f(el4[3]) + s_er[wv][erb + 3]; x = x > 0.f ? x : LEAKY * x; dsum3 += __expf(x);
        }
        #pragma unroll
        for (int m = 32; m; m >>= 1) {
            dsum0 += __shfl_xor(dsum0, m, 64);
            dsum1 += __shfl_xor(dsum1, m, 64);
            dsum2 += __shfl_xor(dsum2, m, 64);
            dsum3 += __shfl_xor(dsum3, m, 64);
        }
        float dh = (h == 0) ? dsum0 : (h == 1) ? dsum1 : (h == 2) ? dsum2 : dsum3;
        float rd = 1.0f / dh;
        float acc = 0.f;
        for (int i = off; i < end; ++i) {
            int rv = rec[i];              // wave-uniform -> broadcast
            int pidx = ((rv & 63) >> 2) * (NN * 64) + (rv >> 6) * 64;
            float x = b2f(elrb[rv + h]) + s_er[wv][(rv & 63) + h];
            x = x > 0.f ? x : LEAKY * x;
            acc = fmaf(__expf(x) * rd, __bfloat162float(projR[pidx + c]), acc);
        }
        out[d * 64 + c] = acc + bias[c];
    }
}

extern "C" void kernel_launch(void* const* d_in, const int* in_sizes, int n_in,
                              void* d_out, int out_size, void* d_ws, size_t ws_size,
                              hipStream_t stream) {
    const float* inputs = (const float*)d_in[0];
    const float* convw  = (const float*)d_in[1];
    const float* attn_l = (const float*)d_in[2];
    const float* attn_r = (const float*)d_in[3];
    const float* h_bias = (const float*)d_in[4];
    const int*   src    = (const int*)d_in[5];
    const int*   dst    = (const int*)d_in[6];
    const int*   rel    = (const int*)d_in[7];
    float* out = (float*)d_out;

    char* ws = (char*)d_ws;
    size_t o = 0;
    bf16* projR  = (bf16*)(ws + o);  o += 102400000ull;   // [8][NN][64]
    short* elrb  = (short*)(ws + o); o += 12800000ull;    // [NN][64] bf16
    short* wxt2  = (short*)(ws + o); o += 147456;
    int2* offdeg = (int2*)(ws + o);  o += 800768;         // NN int2
    int* gCursor = (int*)(ws + o);   o += 2048;
    int* pairbuf = (int*)(ws + o);   o += (size_t)NBUCK * CAP * 4;  // 8,007,680
    int* rec     = (int*)(ws + o);   o += (size_t)NBUCK * CAP * 4;  // 8,007,680

    hipMemsetAsync(gCursor, 0, NBUCK * sizeof(int), stream);
    hipLaunchKernelGGL(wext_scatter, dim3(WEXT_BLOCKS + NSCAT), dim3(256), 0, stream,
                       convw, attn_l, attn_r, wxt2, src, dst, rel, gCursor, pairbuf);
    hipLaunchKernelGGL(gemm_place, dim3(GEMM_BLOCKS + NBUCK), dim3(256), 0, stream,
                       inputs, wxt2, (short*)projR, elrb, gCursor, pairbuf, offdeg, rec);
    hipLaunchKernelGGL(agg, dim3(25000), dim3(256), 0, stream, offdeg, rec, elrb, projR, h_bias, out);
}

// Round 19
// 133.796 us; speedup vs baseline: 1.1186x; 1.1186x over previous
//
#include <hip/hip_runtime.h>
#include <hip/hip_bf16.h>

// HET relational attention layer. (R19 = R17 structure + R18's agg half-wave dedup;
//   CHUNK reverted 2048->4096 — R18 showed smaller chunks double per-block fixed cost
//   and halve pairbuf run lengths, costing ~15us.)
//  memset         : gCursor = 0.
//  K1 wext_scatter: blocks <288 fragment-major W_ext; blocks >=288 bucket_scatter into
//                   FIXED regions (b*CAP), LDS hist + 1 atomic/bucket/block. CHUNK=4096.
//  K2 gemm_place  : blocks <782: gemm (4 waves, 32 rows/wave, 128 rows/block, 576 cols;
//                   A f32->bf16 via XOR-swizzled LDS; B per-cb 16KB LDS w/ reg-prefetch;
//                   C via swizzled LDS -> coalesced PLAIN 1KB stores; projR [rel][node][64],
//                   elrb [node][64] bf16). blocks >=782: exact_place (one per bucket).
//  K3 agg         : 1 wave per dst node; fast path deg<=64: exp once/edge -> LDS,
//                   half-wave-owned edge streams + single end merge (R18-verified:
//                   VALUBusy 61->49%).

#define NN 100000
#define NNP 100096            // 782*128
#define NE 1600000
#define NH 4
#define INF_ 128
#define DH 16
#define NCOL 576
#define LEAKY 0.2f
#define NBUCK 391
#define BSHIFT 8
#define CHUNK 4096
#define NSCAT 391             // ceil(NE/CHUNK)
#define CAP 5120
#define GEMM_BLOCKS 782
#define WEXT_BLOCKS 288

typedef __hip_bfloat16 bf16;
typedef __attribute__((ext_vector_type(8))) short bf16x8;
typedef __attribute__((ext_vector_type(4))) short bf16x4;
typedef __attribute__((ext_vector_type(4))) float f32x4;

static __device__ __forceinline__ short f2bs(float x) {
    bf16 b = __float2bfloat16(x);
    return *reinterpret_cast<short*>(&b);
}
static __device__ __forceinline__ float bflo(unsigned u) { return __uint_as_float(u << 16); }
static __device__ __forceinline__ float bfhi(unsigned u) { return __uint_as_float(u & 0xffff0000u); }
static __device__ __forceinline__ float b2f(short us) {
    return __uint_as_float(((unsigned)(unsigned short)us) << 16);
}

// blocks <288: fragment-major W_ext. blocks >=288: bucket_scatter (gCursor pre-zeroed).
__global__ __launch_bounds__(256) void wext_scatter(
    const float* __restrict__ W, const float* __restrict__ al, const float* __restrict__ ar,
    short* __restrict__ wxt2,
    const int* __restrict__ src, const int* __restrict__ dst, const int* __restrict__ rel,
    int* __restrict__ gCursor, int* __restrict__ pairbuf) {
    __shared__ int hist[NBUCK];
    int t = threadIdx.x;

    if (blockIdx.x >= WEXT_BLOCKS) {
        int blk = blockIdx.x - WEXT_BLOCKS;
        for (int i = t; i < NBUCK; i += 256) hist[i] = 0;
        __syncthreads();
        int base = blk * CHUNK;
        #pragma unroll
        for (int j = 0; j < CHUNK / 256; ++j) {
            int e = base + j * 256 + t;
            if (e < NE) atomicAdd(&hist[dst[e] >> BSHIFT], 1);
        }
        __syncthreads();
        for (int i = t; i < NBUCK; i += 256) {
            int v = hist[i];
            hist[i] = v ? (i * CAP + atomicAdd(&gCursor[i], v)) : 0;
        }
        __syncthreads();
        #pragma unroll
        for (int j = 0; j < CHUNK / 256; ++j) {
            int e = base + j * 256 + t;
            if (e < NE) {
                int d = dst[e];
                int b = d >> BSHIFT;
                int rec = ((d & 255) << 20) | (src[e] * 8 + rel[e]);
                int pos = atomicAdd(&hist[b], 1);
                pairbuf[pos] = rec;
            }
        }
        return;
    }

    int idx = blockIdx.x * 256 + t;
    int e = idx & 7, lane = (idx >> 3) & 63, ct = (idx >> 9) & 3, ks = (idx >> 11) & 3, cb = idx >> 13;
    int g = lane >> 4, r = lane & 15;
    int c = cb * 64 + ct * 16 + r;
    int k = ks * 32 + g * 8 + e;
    float v;
    if (c < 512) {
        int rr = c >> 6, rem = c & 63, h = rem >> 4, d = rem & 15;
        v = W[((rr * NH + h) * INF_ + k) * DH + d];
    } else {
        int rh = c - 512;
        const float* a = al;
        if (rh >= 32) { rh -= 32; a = ar; }
        int rr = rh >> 2, h = rh & 3;
        const float* wp = &W[((rr * NH + h) * INF_ + k) * DH];
        const float* ap = &a[(rr * NH + h) * DH];
        float s = 0.f;
        #pragma unroll
        for (int d = 0; d < DH; ++d) s += wp[d] * ap[d];
        v = s;
    }
    wxt2[idx] = f2bs(v);
}

// Fused: gemm (blocks < GEMM_BLOCKS) + exact_place (blocks >= GEMM_BLOCKS).
__global__ __launch_bounds__(256) void gemm_place(
    const float* __restrict__ A, const short* __restrict__ WxT2,
    short* __restrict__ projR, short* __restrict__ elrb,
    const int* __restrict__ gCursor, const int* __restrict__ pairbuf,
    int2* __restrict__ offdeg, int* __restrict__ rec) {
    __shared__ short As[16384];          // 32 KB: A-tile / C-slices (gemm) or hist/tsum (place)
    __shared__ short Bs[8192];           // 16 KB: current cb's B tile (gemm only)
    int t = threadIdx.x;

    if (blockIdx.x >= GEMM_BLOCKS) {
        // ---- exact_place: one block per bucket (pairbuf complete after K1) ----
        int* hist = (int*)As;
        int* tsum = hist + 256;
        int b = blockIdx.x - GEMM_BLOCKS;
        int start = b * CAP, cnt = gCursor[b];
        hist[t] = 0;
        __syncthreads();
        for (int i = t; i < cnt; i += 256) atomicAdd(&hist[pairbuf[start + i] >> 20], 1);
        __syncthreads();
        int own = hist[t];
        tsum[t] = own;
        __syncthreads();
        for (int st = 1; st < 256; st <<= 1) {
            int y = (t >= st) ? tsum[t - st] : 0;
            __syncthreads();
            tsum[t] += y;
            __syncthreads();
        }
        int excl = start + tsum[t] - own;
        int node = b * 256 + t;
        if (node < NN) offdeg[node] = make_int2(excl, own);
        __syncthreads();
        hist[t] = excl;
        __syncthreads();
        for (int i = t; i < cnt; i += 256) {
            int rc = pairbuf[start + i];
            int pos = atomicAdd(&hist[rc >> 20], 1);
            int sr = rc & 0xFFFFF;
            rec[pos] = (sr >> 3) * 64 + (sr & 7) * 4;   // elrb index; s=rv>>6, r=(rv&63)>>2
        }
        return;
    }

    // ---- gemm: 4 waves, 32 rows/wave, 128 rows/block, all 576 cols; B via LDS pipeline ----
    int wv = t >> 6, lane = t & 63;
    int n0 = blockIdx.x * 128;
    int g = lane >> 4, r = lane & 15;

    #pragma unroll
    for (int j = 0; j < 8; ++j) {
        int i = j * 256 + t;
        int row = i >> 4, c8 = i & 15;
        int gr = n0 + row;
        bf16x8 v;
        if (gr < NN) {
            float4 f0 = *(const float4*)&A[gr * INF_ + c8 * 8];
            float4 f1 = *(const float4*)&A[gr * INF_ + c8 * 8 + 4];
            v[0] = f2bs(f0.x); v[1] = f2bs(f0.y); v[2] = f2bs(f0.z); v[3] = f2bs(f0.w);
            v[4] = f2bs(f1.x); v[5] = f2bs(f1.y); v[6] = f2bs(f1.z); v[7] = f2bs(f1.w);
        } else {
            v = (bf16x8)(short)0;
        }
        *(bf16x8*)&As[(row * 16 + (c8 ^ (row & 7))) * 8] = v;
    }
    // Prefetch cb=0's B into regs (overlaps the staging barrier).
    bf16x8 breg[4];
    #pragma unroll
    for (int q = 0; q < 4; ++q)
        breg[q] = *(const bf16x8*)&WxT2[(q * 256 + t) * 8];
    __syncthreads();

    bf16x8 afr[2][4];
    #pragma unroll
    for (int nt = 0; nt < 2; ++nt) {
        int row = wv * 32 + nt * 16 + r;
        #pragma unroll
        for (int ks = 0; ks < 4; ++ks)
            afr[nt][ks] = *(const bf16x8*)&As[(row * 16 + ((ks * 4 + g) ^ (r & 7))) * 8];
    }
    __syncthreads();                      // A-tile dead; reuse as C-stage
    short* Csh = &As[wv * 4096];          // per-wave 8 KB slice
    int n0w = n0 + wv * 32;

    for (int cb = 0; cb < 9; ++cb) {
        // write-late: B regs -> LDS (Bs free: end-of-prev-cb syncthreads).
        #pragma unroll
        for (int q = 0; q < 4; ++q)
            *(bf16x8*)&Bs[(q * 256 + t) * 8] = breg[q];
        __syncthreads();
        // issue-early: prefetch next cb's B during MFMA + C-stage below.
        if (cb < 8) {
            #pragma unroll
            for (int q = 0; q < 4; ++q)
                breg[q] = *(const bf16x8*)&WxT2[((cb + 1) * 1024 + q * 256 + t) * 8];
        }

        f32x4 acc[2][4] = {};
        #pragma unroll
        for (int ks = 0; ks < 4; ++ks) {
            #pragma unroll
            for (int ct = 0; ct < 4; ++ct) {
                bf16x8 b = *(const bf16x8*)&Bs[((ks * 4 + ct) * 64 + lane) * 8];
                acc[0][ct] = __builtin_amdgcn_mfma_f32_16x16x32_bf16(b, afr[0][ks], acc[0][ct], 0, 0, 0);
                acc[1][ct] = __builtin_amdgcn_mfma_f32_16x16x32_bf16(b, afr[1][ks], acc[1][ct], 0, 0, 0);
            }
        }
        // lane(g,r), reg q: row = n0w + nt*16 + r, col = cb*64 + ct*16 + g*4 + q.
        // Unified bf16 C-stage: cb<8 -> projR[cb][node][64]; cb==8 -> elrb[node][64].
        #pragma unroll
        for (int nt = 0; nt < 2; ++nt) {
            int rr = nt * 16 + r;
            #pragma unroll
            for (int ct = 0; ct < 4; ++ct) {
                bf16x4 p;
                p[0] = f2bs(acc[nt][ct][0]); p[1] = f2bs(acc[nt][ct][1]);
                p[2] = f2bs(acc[nt][ct][2]); p[3] = f2bs(acc[nt][ct][3]);
                *(bf16x4*)&Csh[rr * 64 + (((ct * 4 + g) ^ ((rr & 7) << 1)) << 2)] = p;
            }
        }
        __builtin_amdgcn_wave_barrier();
        short* dstbase = (cb < 8) ? &projR[((size_t)cb * NN + n0w) * 64]
                                  : &elrb[(size_t)n0w * 64];
        #pragma unroll
        for (int q = 0; q < 4; ++q) {
            int rr = (lane >> 3) + q * 8;
            if (n0w + rr < NN) {
                bf16x8 vv = *(const bf16x8*)&Csh[rr * 64 + (((lane & 7) ^ (rr & 7)) << 3)];
                *(bf16x8*)&dstbase[q * 512 + lane * 8] = vv;
            }
        }
        __syncthreads();                  // C-stage read done AND B reads done before next cb
    }
}

__global__ __launch_bounds__(256) void agg(
    const int2* __restrict__ offdeg, const int* __restrict__ rec,
    const short* __restrict__ elrb, const bf16* __restrict__ projR,
    const float* __restrict__ bias, float* __restrict__ out) {
    __shared__ float s_alpha[4][64][4];
    __shared__ int   s_pidx[4][64];
    __shared__ float s_er[4][32];
    int wv = threadIdx.x >> 6, lane = threadIdx.x & 63;
    int d = blockIdx.x * 4 + wv;
    if (d >= NN) return;
    int2 od = offdeg[d];
    int off = od.x, deg = od.y;
    int end = off + deg;

    if (lane < 32) s_er[wv][lane] = b2f(elrb[d * 64 + 32 + lane]);
    __builtin_amdgcn_wave_barrier();
    asm volatile("s_waitcnt lgkmcnt(0)" ::: "memory");

    if (deg == 0) {
        if (lane < 32) {
            float2 bb = *(const float2*)&bias[lane * 2];
            *(float2*)&out[d * 64 + lane * 2] = bb;
        }
    } else if (deg <= 64) {
        int i = off + lane;
        float e0 = 0.f, e1 = 0.f, e2 = 0.f, e3 = 0.f;
        int pidx = 0;
        if (i < end) {
            int rv = rec[i];
            pidx = ((rv & 63) >> 2) * (NN * 64) + (rv >> 6) * 64;
            bf16x4 el4 = *(const bf16x4*)&elrb[rv];
            int erb = rv & 63;            // r*4
            float x;
            x = b2f(el4[0]) + s_er[wv][erb + 0]; x = x > 0.f ? x : LEAKY * x; e0 = __expf(x);
            x = b2f(el4[1]) + s_er[wv][erb + 1]; x = x > 0.f ? x : LEAKY * x; e1 = __expf(x);
            x = b2f(el4[2]) + s_er[wv][erb + 2]; x = x > 0.f ? x : LEAKY * x; e2 = __expf(x);
            x = b2f(el4[3]) + s_er[wv][erb + 3]; x = x > 0.f ? x : LEAKY * x; e3 = __expf(x);
        }
        s_pidx[wv][lane] = pidx;
        *(float4*)&s_alpha[wv][lane][0] = make_float4(e0, e1, e2, e3);
        __builtin_amdgcn_wave_barrier();
        asm volatile("s_waitcnt lgkmcnt(0)" ::: "memory");

        // pass B: half-wave hl owns edge stream (j+hl per pair); cols 2c,2c+1;
        // single cross-half merge at the end.
        int col2 = (lane & 31) * 2;
        int hl = lane >> 5;
        int h2 = (lane & 31) >> 3;
        float acc0 = 0.f, acc1 = 0.f, dsum = 0.f;
        int j = 0;
        for (; j + 8 <= deg; j += 8) {        // 4 loads in flight, own-edge only
            unsigned uu[4];
            float aa[4];
            #pragma unroll
            for (int p = 0; p < 4; ++p) {
                int eidx = j + 2 * p + hl;
                uu[p] = *(const unsigned*)&projR[s_pidx[wv][eidx] + col2];
                aa[p] = s_alpha[wv][eidx][h2];
            }
            #pragma unroll
            for (int p = 0; p < 4; ++p) {
                acc0 = fmaf(aa[p], bflo(uu[p]), acc0);
                acc1 = fmaf(aa[p], bfhi(uu[p]), acc1);
                dsum += aa[p];
            }
        }
        for (; j + 2 <= deg; j += 2) {
            int eidx = j + hl;
            unsigned u = *(const unsigned*)&projR[s_pidx[wv][eidx] + col2];
            float a = s_alpha[wv][eidx][h2];
            acc0 = fmaf(a, bflo(u), acc0);
            acc1 = fmaf(a, bfhi(u), acc1);
            dsum += a;
        }
        if (j < deg && hl == 0) {             // odd tail: low half only
            unsigned u = *(const unsigned*)&projR[s_pidx[wv][j] + col2];
            float a = s_alpha[wv][j][h2];
            acc0 = fmaf(a, bflo(u), acc0);
            acc1 = fmaf(a, bfhi(u), acc1);
            dsum += a;
        }
        acc0 += __shfl_xor(acc0, 32);
        acc1 += __shfl_xor(acc1, 32);
        dsum += __shfl_xor(dsum, 32);
        if (lane < 32) {
            float inv = 1.0f / dsum;
            float2 bb = *(const float2*)&bias[col2];
            float2 o;
            o.x = acc0 * inv + bb.x;
            o.y = acc1 * inv + bb.y;
            *(float2*)&out[d * 64 + col2] = o;
        }
    } else {
        int c = lane, h = c >> 4;
        float dsum0 = 0.f, dsum1 = 0.f, dsum2 = 0.f, dsum3 = 0.f;
        for (int i = off + lane; i < end; i += 64) {
            int rv = rec[i];
            bf16x4 el4 = *(const bf16x4*)&elrb[rv];
            int erb = rv & 63;
            float x;
            x = b2f(el4[0]) + s_er[wv][erb + 0]; x = x > 0.f ? x : LEAKY * x; dsum0 += __expf(x);
            x = b2f(el4[1]) + s_er[wv][erb + 1]; x = x > 0.f ? x : LEAKY * x; dsum1 += __expf(x);
            x = b2f(el4[2]) + s_er[wv][erb + 2]; x = x > 0.f ? x : LEAKY * x; dsum2 += __expf(x);
            x = b2f(el4[3]) + s_er[wv][erb + 3]; x = x > 0.f ? x : LEAKY * x; dsum3 += __expf(x);
        }
        #pragma unroll
        for (int m = 32; m; m >>= 1) {
            dsum0 += __shfl_xor(dsum0, m, 64);
            dsum1 += __shfl_xor(dsum1, m, 64);
            dsum2 += __shfl_xor(dsum2, m, 64);
            dsum3 += __shfl_xor(dsum3, m, 64);
        }
        float dh = (h == 0) ? dsum0 : (h == 1) ? dsum1 : (h == 2) ? dsum2 : dsum3;
        float rd = 1.0f / dh;
        float acc = 0.f;
        for (int i = off; i < end; ++i) {
            int rv = rec[i];              // wave-uniform -> broadcast
            int pidx = ((rv & 63) >> 2) * (NN * 64) + (rv >> 6) * 64;
            float x = b2f(elrb[rv + h]) + s_er[wv][(rv & 63) + h];
            x = x > 0.f ? x : LEAKY * x;
            acc = fmaf(__expf(x) * rd, __bfloat162float(projR[pidx + c]), acc);
        }
        out[d * 64 + c] = acc + bias[c];
    }
}

extern "C" void kernel_launch(void* const* d_in, const int* in_sizes, int n_in,
                              void* d_out, int out_size, void* d_ws, size_t ws_size,
                              hipStream_t stream) {
    const float* inputs = (const float*)d_in[0];
    const float* convw  = (const float*)d_in[1];
    const float* attn_l = (const float*)d_in[2];
    const float* attn_r = (const float*)d_in[3];
    const float* h_bias = (const float*)d_in[4];
    const int*   src    = (const int*)d_in[5];
    const int*   dst    = (const int*)d_in[6];
    const int*   rel    = (const int*)d_in[7];
    float* out = (float*)d_out;

    char* ws = (char*)d_ws;
    size_t o = 0;
    bf16* projR  = (bf16*)(ws + o);  o += 102400000ull;   // [8][NN][64]
    short* elrb  = (short*)(ws + o); o += 12800000ull;    // [NN][64] bf16
    short* wxt2  = (short*)(ws + o); o += 147456;
    int2* offdeg = (int2*)(ws + o);  o += 800768;         // NN int2
    int* gCursor = (int*)(ws + o);   o += 2048;
    int* pairbuf = (int*)(ws + o);   o += (size_t)NBUCK * CAP * 4;  // 8,007,680
    int* rec     = (int*)(ws + o);   o += (size_t)NBUCK * CAP * 4;  // 8,007,680

    hipMemsetAsync(gCursor, 0, NBUCK * sizeof(int), stream);
    hipLaunchKernelGGL(wext_scatter, dim3(WEXT_BLOCKS + NSCAT), dim3(256), 0, stream,
                       convw, attn_l, attn_r, wxt2, src, dst, rel, gCursor, pairbuf);
    hipLaunchKernelGGL(gemm_place, dim3(GEMM_BLOCKS + NBUCK), dim3(256), 0, stream,
                       inputs, wxt2, (short*)projR, elrb, gCursor, pairbuf, offdeg, rec);
    hipLaunchKernelGGL(agg, dim3(25000), dim3(256), 0, stream, offdeg, rec, elrb, projR, h_bias, out);
}